// Round 16
// baseline (1192.689 us; speedup 1.0000x reference)
//
#include <hip/hip_runtime.h>

#define NN 50000
#define BLK_E 4096   // edges per block in passes A/C (256 thr x 16)

typedef short bf16x8 __attribute__((ext_vector_type(8)));
typedef float f32x16 __attribute__((ext_vector_type(16)));

__device__ __forceinline__ unsigned bf16r(float f) {   // RNE round to bf16
    unsigned u = __float_as_uint(f);
    return (u + 0x7FFFu + ((u >> 16) & 1u)) >> 16;
}
__device__ __forceinline__ float bflo(unsigned u) { return __uint_as_float(u << 16); }
__device__ __forceinline__ float bfhi(unsigned u) { return __uint_as_float(u & 0xFFFF0000u); }

// ---------------- pass A: per-block dst>>8 histogram (+ W/x bf16 converts) ----

__global__ void passA_k(const int* __restrict__ ei, int E,
                        int* __restrict__ counts, int nebl,
                        const float* __restrict__ Wl, const float* __restrict__ Wr,
                        uint* __restrict__ wb,
                        const float* __restrict__ x, uint* __restrict__ xb, int nquad) {
    int bid = blockIdx.x;
    int t = threadIdx.x;
    if (bid < nebl) {
        __shared__ int dh[256];
        dh[t] = 0;
        __syncthreads();
        const int* dst = ei + E;
        int base = bid * BLK_E + t * 16;
        if (base + 16 <= E) {
            #pragma unroll
            for (int q = 0; q < 4; ++q) {
                int4 d4 = *(const int4*)(dst + base + q * 4);
                atomicAdd(&dh[d4.x >> 8], 1);
                atomicAdd(&dh[d4.y >> 8], 1);
                atomicAdd(&dh[d4.z >> 8], 1);
                atomicAdd(&dh[d4.w >> 8], 1);
            }
        } else {
            for (int e = base; e < E; ++e) atomicAdd(&dh[dst[e] >> 8], 1);
        }
        __syncthreads();
        counts[bid * 256 + t] = dh[t];
    } else if (bid < nebl + 64) {
        int i = (bid - nebl) * 256 + t;           // 0..16383
        int nrow = i >> 7;
        int k = (i & 127) * 2;
        const float* W = (k < 128) ? Wl : Wr;
        int kk = k & 127;
        uint lo = bf16r(W[nrow * 128 + kk]);
        uint hi = bf16r(W[nrow * 128 + kk + 1]);
        wb[i] = (hi << 16) | lo;
    } else {
        int i = (bid - nebl - 64) * 256 + t;
        if (i >= nquad) return;
        float4 v = ((const float4*)x)[i];
        uint2 p;
        p.x = (bf16r(v.y) << 16) | bf16r(v.x);
        p.y = (bf16r(v.w) << 16) | bf16r(v.z);
        ((uint2*)xb)[i] = p;
    }
}

// ---------------- pass B: column-exclusive prefix + bin bases ----------------

__global__ void passB_k(int* __restrict__ counts, int nebl,
                        int* __restrict__ binBase) {
    __shared__ int sm[256];
    int t = threadIdx.x;
    int run = 0;
    for (int b = 0; b < nebl; b += 8) {
        int v[8];
        #pragma unroll
        for (int j = 0; j < 8; ++j)
            v[j] = (b + j < nebl) ? counts[(b + j) * 256 + t] : 0;
        #pragma unroll
        for (int j = 0; j < 8; ++j) {
            if (b + j < nebl) counts[(b + j) * 256 + t] = run;
            run += v[j];
        }
    }
    int v = run;                      // column total
    sm[t] = v;
    __syncthreads();
    for (int off = 1; off < 256; off <<= 1) {
        int a = (t >= off) ? sm[t - off] : 0;
        __syncthreads();
        sm[t] += a;
        __syncthreads();
    }
    binBase[t] = sm[t] - v;           // exclusive
    if (t == 255) binBase[256] = sm[255];   // == E
}

// ---------------- pass C: scatter edges into dst>>8 partitions --------------
// upack = (dst&255)<<16 | src  (src < 50000 < 2^16)

__global__ void passC_k(const int* __restrict__ ei, int E,
                        const int* __restrict__ counts,
                        const int* __restrict__ binBase,
                        uint* __restrict__ upack, int nebl) {
    __shared__ int cur[256];
    int t = threadIdx.x, bid = blockIdx.x;
    cur[t] = counts[bid * 256 + t] + binBase[t];
    __syncthreads();
    const int* dst = ei + E;
    const int* src = ei;
    int base = bid * BLK_E + t * 16;
    if (base + 16 <= E) {
        #pragma unroll
        for (int q = 0; q < 4; ++q) {
            int4 d4 = *(const int4*)(dst + base + q * 4);
            int4 s4 = *(const int4*)(src + base + q * 4);
            int p;
            p = atomicAdd(&cur[d4.x >> 8], 1);
            upack[p] = ((uint)(d4.x & 255) << 16) | (uint)s4.x;
            p = atomicAdd(&cur[d4.y >> 8], 1);
            upack[p] = ((uint)(d4.y & 255) << 16) | (uint)s4.y;
            p = atomicAdd(&cur[d4.z >> 8], 1);
            upack[p] = ((uint)(d4.z & 255) << 16) | (uint)s4.z;
            p = atomicAdd(&cur[d4.w >> 8], 1);
            upack[p] = ((uint)(d4.w & 255) << 16) | (uint)s4.w;
        }
    } else {
        for (int e = base; e < E; ++e) {
            int d = dst[e];
            int p = atomicAdd(&cur[d >> 8], 1);
            upack[p] = ((uint)(d & 255) << 16) | (uint)src[e];
        }
    }
}

// ---------------- fused layer v2: EDGE-PARALLEL LDS aggregation + MFMA -------
// Block = one 256-node partition, 1024 threads, acc[256][128] f32 in 128KB
// dynamic LDS (granule-XOR swizzle). Sweep: 64 edge-slots x 16 col-lanes,
// every gather independent (node-parallel dependent chains were the measured
// ~50us cap; hipcc never pipelines them — R9/R10/R15). ds_add_f32 floor
// ~5.5us/block; no max-degree straggler; passD deleted (reads upack direct).
// Phase 2: 16 waves = 8 m-tiles x 2 col-pairs; A from swizzled acc (x 1/deg,
// bf16-rounded — same quantization as before), self-rows + W from global.

#define ADD_EDGE(u, v)                                                        \
    {                                                                         \
        int ld_ = (int)((u) >> 16);                                           \
        int b0_ = ld_ * 128 + (((c16 * 2) ^ (ld_ & 7)) << 2);                 \
        int b1_ = ld_ * 128 + (((c16 * 2 + 1) ^ (ld_ & 7)) << 2);             \
        atomicAdd(&acc[b0_ + 0], bflo((v).x));                                \
        atomicAdd(&acc[b0_ + 1], bfhi((v).x));                                \
        atomicAdd(&acc[b0_ + 2], bflo((v).y));                                \
        atomicAdd(&acc[b0_ + 3], bfhi((v).y));                                \
        atomicAdd(&acc[b1_ + 0], bflo((v).z));                                \
        atomicAdd(&acc[b1_ + 1], bfhi((v).z));                                \
        atomicAdd(&acc[b1_ + 2], bflo((v).w));                                \
        atomicAdd(&acc[b1_ + 3], bfhi((v).w));                                \
        if (c16 == 0) atomicAdd(&ideg[ld_], 1);                               \
    }

__global__ __launch_bounds__(1024) void fused_layer_k(
    const uint4* __restrict__ in4,    // bf16 rows [N][16 uint4]
    const int* __restrict__ binBase,  // [197] partition edge ranges
    const uint* __restrict__ upack,   // partition-sorted (local<<16)|src
    const ushort* __restrict__ Wb,    // [128][256] bf16
    const float* __restrict__ bl,
    float* __restrict__ out,          // f32 out or null
    ushort* __restrict__ hb,          // bf16 out or null
    int N, int relu) {
    extern __shared__ float acc[];            // [256][128] f32, swizzled
    int* ideg = (int*)(acc + 32768);          // [256]

    int tid = threadIdx.x;
    int p   = blockIdx.x;

    // zero acc + ideg (8192 + 64 uint4)
    uint4 z = {0, 0, 0, 0};
    uint4* az = (uint4*)acc;
    for (int i = tid; i < 8256; i += 1024) az[i] = z;
    __syncthreads();

    // ---- edge sweep ----
    int s0 = binBase[p], s1 = binBase[p + 1];
    int eg = tid >> 4, c16 = tid & 15;
    for (int e = s0 + eg; e < s1; e += 256) {
        int e1 = min(e + 64,  s1 - 1);
        int e2 = min(e + 128, s1 - 1);
        int e3 = min(e + 192, s1 - 1);
        uint u0 = upack[e],  u1 = upack[e1];
        uint u2 = upack[e2], u3 = upack[e3];
        uint4 r0 = in4[(size_t)(u0 & 0xFFFFu) * 16 + c16];
        uint4 r1 = in4[(size_t)(u1 & 0xFFFFu) * 16 + c16];
        uint4 r2 = in4[(size_t)(u2 & 0xFFFFu) * 16 + c16];
        uint4 r3 = in4[(size_t)(u3 & 0xFFFFu) * 16 + c16];
        ADD_EDGE(u0, r0);
        if (e + 64  < s1) ADD_EDGE(u1, r1);
        if (e + 128 < s1) ADD_EDGE(u2, r2);
        if (e + 192 < s1) ADD_EDGE(u3, r3);
    }
    __syncthreads();

    // ---- MFMA phase: 16 waves = 8 m-tiles x 2 col-pairs ----
    int wid   = tid >> 6;
    int lane  = tid & 63;
    int mrow  = lane & 31;
    int khalf = lane >> 5;
    int mtile = wid >> 1;
    int ctb   = (wid & 1) * 2;
    int ld    = mtile * 32 + mrow;

    int dgv = ideg[ld];
    float inv = (dgv > 0) ? (1.f / (float)dgv) : 0.f;

    union { uint4 u; bf16x8 v; } cv;
    bf16x8 A[16];
    #pragma unroll
    for (int ks = 0; ks < 8; ++ks) {
        int gb = ks * 4 + khalf * 2;
        int g0 = gb ^ (ld & 7);
        int g1 = (gb + 1) ^ (ld & 7);
        float4 f0 = *(float4*)&acc[ld * 128 + g0 * 4];
        float4 f1 = *(float4*)&acc[ld * 128 + g1 * 4];
        cv.u.x = (bf16r(f0.y * inv) << 16) | bf16r(f0.x * inv);
        cv.u.y = (bf16r(f0.w * inv) << 16) | bf16r(f0.z * inv);
        cv.u.z = (bf16r(f1.y * inv) << 16) | bf16r(f1.x * inv);
        cv.u.w = (bf16r(f1.w * inv) << 16) | bf16r(f1.z * inv);
        A[ks] = cv.v;
    }
    int gm0 = p * 256 + ld;
    if (gm0 >= N) gm0 = N - 1;
    const ushort* ar1 = (const ushort*)in4 + (size_t)gm0 * 128 + khalf * 8;
    #pragma unroll
    for (int ks = 0; ks < 8; ++ks)
        A[8 + ks] = *reinterpret_cast<const bf16x8*>(ar1 + ks * 16);

    for (int ct = ctb; ct < ctb + 2; ++ct) {
        int nfeat = ct * 32 + mrow;
        bf16x8 B[16];
        const ushort* wrow = Wb + (size_t)nfeat * 256 + khalf * 8;
        #pragma unroll
        for (int ks = 0; ks < 16; ++ks)
            B[ks] = *reinterpret_cast<const bf16x8*>(wrow + ks * 16);

        f32x16 c = {};
        #pragma unroll
        for (int ks = 0; ks < 16; ++ks)
            c = __builtin_amdgcn_mfma_f32_32x32x16_bf16(A[ks], B[ks], c, 0, 0, 0);

        float bias = bl[nfeat];
        #pragma unroll
        for (int r2 = 0; r2 < 16; ++r2) {
            int rr = (r2 & 3) + 8 * (r2 >> 2) + 4 * khalf;
            int gm = p * 256 + mtile * 32 + rr;
            if (gm < N) {
                float vv = c[r2] + bias;
                if (relu) vv = fmaxf(vv, 0.f);
                if (out) out[(size_t)gm * 128 + nfeat] = vv;
                if (hb)  hb[(size_t)gm * 128 + nfeat] = (ushort)bf16r(vv);
            }
        }
    }
}

extern "C" void kernel_launch(void* const* d_in, const int* in_sizes, int n_in,
                              void* d_out, int out_size, void* d_ws, size_t ws_size,
                              hipStream_t stream) {
    const float* x  = (const float*)d_in[0];
    const int*   ei = (const int*)d_in[1];
    const float* Wl = (const float*)d_in[2];
    const float* bl = (const float*)d_in[3];
    const float* Wr = (const float*)d_in[4];
    float* out = (float*)d_out;

    const int N = NN;
    const int E = in_sizes[1] / 2;
    const int NPAD = 50016;

    int nebl = (E + BLK_E - 1) / BLK_E;       // 157
    int nprt = (N + 255) / 256;               // 196 partitions

    // ws layout (u32 units):
    // counts[nebl*256] | binBase[260] | upack[E] | wb[16384]
    // | xb[NPAD*64] | hb[NPAD*64]
    int*  ws      = (int*)d_ws;
    int*  counts  = ws;
    int*  binBase = counts + nebl * 256;
    uint* upack   = (uint*)(binBase + 260);
    uint* wb      = (uint*)(upack + E);
    uint* xb      = wb + 128 * 128;
    uint* hb      = xb + (size_t)NPAD * 64;

    int nquad = N * 32;
    int cvtb  = (nquad + 255) / 256;

    (void)hipFuncSetAttribute((const void*)fused_layer_k,
                              hipFuncAttributeMaxDynamicSharedMemorySize, 132096);

    passA_k<<<nebl + 64 + cvtb, 256, 0, stream>>>(ei, E, counts, nebl,
                                                  Wl, Wr, wb, x, xb, nquad);
    passB_k<<<1, 256, 0, stream>>>(counts, nebl, binBase);
    passC_k<<<nebl, 256, 0, stream>>>(ei, E, counts, binBase, upack, nebl);

    // layer 1: gather from xb, output bf16 hb only
    fused_layer_k<<<nprt, 1024, 132096, stream>>>((const uint4*)xb, binBase, upack,
                                                  (const ushort*)wb, bl,
                                                  (float*)nullptr, (ushort*)hb, N, 1);
    // layer 2: gather from hb, output f32 out
    fused_layer_k<<<nprt, 1024, 132096, stream>>>((const uint4*)hb, binBase, upack,
                                                  (const ushort*)wb, bl,
                                                  out, (ushort*)nullptr, N, 0);
}